// Round 14
// baseline (1156.183 us; speedup 1.0000x reference)
//
#include <hip/hip_runtime.h>
#include <cstdint>
#include <cstddef>

#define LQ     2048
#define DM     256
#define NKEY   16384
#define NLVL   4
#define LVLN   4096
#define BM8    128
#define BN8    128
#define KB     16
#define CLIPMX 3969
#define QB     8

// ---------- branchless sorted-insert into top-4, register-only ----------
// strict: later-inserted equal values lose (valid when idx inserted ascending)
__device__ __forceinline__ void ins4(float v, int ix, float4& tv, int4& ti) {
  bool c0 = v > tv.x, c1 = v > tv.y, c2 = v > tv.z, c3 = v > tv.w;
  tv.w = c2 ? tv.z : (c3 ? v : tv.w);
  ti.w = c2 ? ti.z : (c3 ? ix : ti.w);
  tv.z = c1 ? tv.y : (c2 ? v : tv.z);
  ti.z = c1 ? ti.y : (c2 ? ix : ti.z);
  tv.y = c0 ? tv.x : (c1 ? v : tv.y);
  ti.y = c0 ? ti.x : (c1 ? ix : ti.y);
  tv.x = c0 ? v : tv.x;
  ti.x = c0 ? ix : ti.x;
}

// tie-break: equal value -> smaller index wins (numpy/jax top_k semantics)
__device__ __forceinline__ void ins4_tb(float v, int ix, float4& tv, int4& ti) {
  bool c0 = (v > tv.x) || (v == tv.x && ix < ti.x);
  bool c1 = (v > tv.y) || (v == tv.y && ix < ti.y);
  bool c2 = (v > tv.z) || (v == tv.z && ix < ti.z);
  bool c3 = (v > tv.w) || (v == tv.w && ix < ti.w);
  tv.w = c2 ? tv.z : (c3 ? v : tv.w);
  ti.w = c2 ? ti.z : (c3 ? ix : ti.w);
  tv.z = c1 ? tv.y : (c2 ? v : tv.z);
  ti.z = c1 ? ti.y : (c2 ? ix : ti.z);
  tv.y = c0 ? tv.x : (c1 ? v : tv.y);
  ti.y = c0 ? ti.x : (c1 ? ix : ti.y);
  tv.x = c0 ? v : tv.x;
  ti.x = c0 ? ix : ti.x;
}

// vector helpers (functions, not macros — macro-hygiene lesson from round 12)
__device__ __forceinline__ void fma4v(float4& acc, float s, const float4& v) {
  acc.x = fmaf(s, v.x, acc.x);
  acc.y = fmaf(s, v.y, acc.y);
  acc.z = fmaf(s, v.z, acc.z);
  acc.w = fmaf(s, v.w, acc.w);
}
__device__ __forceinline__ void add4(float4& acc, const float4& v) {
  acc.x += v.x; acc.y += v.y; acc.z += v.z; acc.w += v.w;
}

#define FMA4(accv, s, bv)                  \
  accv.x = fmaf(s, bv.x, accv.x);          \
  accv.y = fmaf(s, bv.y, accv.y);          \
  accv.z = fmaf(s, bv.z, accv.z);          \
  accv.w = fmaf(s, bv.w, accv.w);

// 128x16 staging per array: 512 float4 chunks; thread t covers chunks 2t, 2t+1
// (row = tid>>1, k-slots s2, s2+1 where s2 = (tid&1)*2)
#define GLOAD8(ko)                                                            \
    aR0 = *(const float4*)(Aslab + (size_t)r2 * DM + (ko) + s2 * 4);          \
    aR1 = *(const float4*)(Aslab + (size_t)r2 * DM + (ko) + s2 * 4 + 4);      \
    bR0 = *(const float4*)(Bslab + (size_t)r2 * DM + (ko) + s2 * 4);          \
    bR1 = *(const float4*)(Bslab + (size_t)r2 * DM + (ko) + s2 * 4 + 4);

#define LSTORE8(nb_)                                                          \
    As[nb_][s2*4+0][r2] = aR0.x; As[nb_][s2*4+1][r2] = aR0.y;                 \
    As[nb_][s2*4+2][r2] = aR0.z; As[nb_][s2*4+3][r2] = aR0.w;                 \
    As[nb_][s2*4+4][r2] = aR1.x; As[nb_][s2*4+5][r2] = aR1.y;                 \
    As[nb_][s2*4+6][r2] = aR1.z; As[nb_][s2*4+7][r2] = aR1.w;                 \
    Bs[nb_][s2*4+0][r2] = bR0.x; Bs[nb_][s2*4+1][r2] = bR0.y;                 \
    Bs[nb_][s2*4+2][r2] = bR0.z; Bs[nb_][s2*4+3][r2] = bR0.w;                 \
    Bs[nb_][s2*4+4][r2] = bR1.x; Bs[nb_][s2*4+5][r2] = bR1.y;                 \
    Bs[nb_][s2*4+6][r2] = bR1.z; Bs[nb_][s2*4+7][r2] = bR1.w;

// ---------- kernel A: fp32 GEMM 128x128 tile, 8x8 micro, KB=16, (256,2) ----------
// per k-iter: 4 b128 LDS reads for 64 FMAs (4 FMA/float, vs 2.67 at 4x8)
__global__ __launch_bounds__(256, 2) void gemm_qk8(
    const float* __restrict__ Qm, const float* __restrict__ Kb,
    float* __restrict__ C)
{
  const int tid  = threadIdx.x;
  const int mgrp = blockIdx.x;
  const int nb2  = blockIdx.y;
  const int ty = tid >> 4, tx = tid & 15;
  const int r2 = tid >> 1, s2 = (tid & 1) * 2;

  __shared__ __align__(16) float As[2][KB][BM8 + 4];   // 2*16*132*4 = 16.9 KB
  __shared__ __align__(16) float Bs[2][KB][BN8 + 4];   // 16.9 KB

  const float* Aslab = Qm + (size_t)mgrp * BM8 * DM;
  const float* Bslab = Kb + (size_t)nb2 * BN8 * DM;

  float4 a0l = {0,0,0,0}, a1l = {0,0,0,0}, a2l = {0,0,0,0}, a3l = {0,0,0,0};
  float4 a4l = {0,0,0,0}, a5l = {0,0,0,0}, a6l = {0,0,0,0}, a7l = {0,0,0,0};
  float4 a0h = {0,0,0,0}, a1h = {0,0,0,0}, a2h = {0,0,0,0}, a3h = {0,0,0,0};
  float4 a4h = {0,0,0,0}, a5h = {0,0,0,0}, a6h = {0,0,0,0}, a7h = {0,0,0,0};

  float4 aR0, aR1, bR0, bR1;

  GLOAD8(0)
  LSTORE8(0)

#pragma unroll 1
  for (int kc = 0; kc < DM / KB; ++kc) {
    __syncthreads();
    if (kc < DM / KB - 1) {
      GLOAD8((kc + 1) * KB)
    }
    const int buf = kc & 1;
#pragma unroll
    for (int k = 0; k < KB; ++k) {
      const float4 av0 = *(const float4*)&As[buf][k][ty * 8];
      const float4 av1 = *(const float4*)&As[buf][k][ty * 8 + 4];
      const float4 b0  = *(const float4*)&Bs[buf][k][tx * 4];
      const float4 b1  = *(const float4*)&Bs[buf][k][64 + tx * 4];
      FMA4(a0l, av0.x, b0) FMA4(a0h, av0.x, b1)
      FMA4(a1l, av0.y, b0) FMA4(a1h, av0.y, b1)
      FMA4(a2l, av0.z, b0) FMA4(a2h, av0.z, b1)
      FMA4(a3l, av0.w, b0) FMA4(a3h, av0.w, b1)
      FMA4(a4l, av1.x, b0) FMA4(a4h, av1.x, b1)
      FMA4(a5l, av1.y, b0) FMA4(a5h, av1.y, b1)
      FMA4(a6l, av1.z, b0) FMA4(a6h, av1.z, b1)
      FMA4(a7l, av1.w, b0) FMA4(a7h, av1.w, b1)
    }
    if (kc < DM / KB - 1) {
      LSTORE8((kc & 1) ^ 1)
    }
  }

  float* Cp = C + (size_t)(mgrp * BM8 + ty * 8) * LVLN + nb2 * BN8 + tx * 4;
  *(float4*)(Cp + 0 * LVLN) = a0l;  *(float4*)(Cp + 0 * LVLN + 64) = a0h;
  *(float4*)(Cp + 1 * LVLN) = a1l;  *(float4*)(Cp + 1 * LVLN + 64) = a1h;
  *(float4*)(Cp + 2 * LVLN) = a2l;  *(float4*)(Cp + 2 * LVLN + 64) = a2h;
  *(float4*)(Cp + 3 * LVLN) = a3l;  *(float4*)(Cp + 3 * LVLN + 64) = a3h;
  *(float4*)(Cp + 4 * LVLN) = a4l;  *(float4*)(Cp + 4 * LVLN + 64) = a4h;
  *(float4*)(Cp + 5 * LVLN) = a5l;  *(float4*)(Cp + 5 * LVLN + 64) = a5h;
  *(float4*)(Cp + 6 * LVLN) = a6l;  *(float4*)(Cp + 6 * LVLN + 64) = a6h;
  *(float4*)(Cp + 7 * LVLN) = a7l;  *(float4*)(Cp + 7 * LVLN + 64) = a7h;
}

// ---------- kernel B: per-(q,level) top-4 + emit tix/sloc (proven) ----------
__global__ __launch_bounds__(256) void topk_loc(
    const float* __restrict__ C, const int lvl,
    int* __restrict__ tix, float* __restrict__ sloc)
{
  const int wid  = threadIdx.x >> 6;
  const int lane = threadIdx.x & 63;
  const int q = blockIdx.x * 4 + wid;
  const float* row = C + (size_t)q * LVLN;

  const float4 NEGI = {-3.4e38f, -3.4e38f, -3.4e38f, -3.4e38f};
  const int4   MAXI = {0x7fffffff, 0x7fffffff, 0x7fffffff, 0x7fffffff};
  float4 tv = NEGI;
  int4   ti = MAXI;

#pragma unroll
  for (int it = 0; it < 16; ++it) {
    const int col = it * 256 + lane * 4;
    const float4 v = *(const float4*)(row + col);
    ins4(v.x, col + 0, tv, ti);
    ins4(v.y, col + 1, tv, ti);
    ins4(v.z, col + 2, tv, ti);
    ins4(v.w, col + 3, tv, ti);
  }
#pragma unroll
  for (int d = 1; d < 64; d <<= 1) {
    const float ovx = __shfl_xor(tv.x, d), ovy = __shfl_xor(tv.y, d),
                ovz = __shfl_xor(tv.z, d), ovw = __shfl_xor(tv.w, d);
    const int   oix = __shfl_xor(ti.x, d), oiy = __shfl_xor(ti.y, d),
                oiz = __shfl_xor(ti.z, d), oiw = __shfl_xor(ti.w, d);
    ins4_tb(ovx, oix, tv, ti);
    ins4_tb(ovy, oiy, tv, ti);
    ins4_tb(ovz, oiz, tv, ti);
    ins4_tb(ovw, oiw, tv, ti);
  }

  const int g = q * NLVL + lvl;
  if (lane < 4) {
    const int li = lane == 0 ? ti.x : (lane == 1 ? ti.y : (lane == 2 ? ti.z : ti.w));
    tix[g * 4 + lane] = li;
  }
  if (lane < 36) {
    const int p  = lane & 3, n9 = lane >> 2;
    const int li = p == 0 ? ti.x : (p == 1 ? ti.y : (p == 2 ? ti.z : ti.w));
    const int dy = n9 / 3 - 1, dx = n9 % 3 - 1;
    int r = li + dy * 64 + dx;
    r = r < 0 ? 0 : (r > CLIPMX ? CLIPMX : r);
    sloc[(size_t)g * 72 + lane * 2 + 0] = (float)(r >> 6) * 0.015625f;
    sloc[(size_t)g * 72 + lane * 2 + 1] = (float)(r & 63) * 0.015625f;
  }
}

// ---------- kernel C: gather, parallel over (q, level, point), float4 channels ----------
__global__ __launch_bounds__(256) void samp_acc4(
    const float* __restrict__ V, const int* __restrict__ tix,
    float* __restrict__ pre4)
{
  const int q = blockIdx.x, l = blockIdx.y;
  const int p = threadIdx.x >> 6, lane = threadIdx.x & 63;
  const int c0 = lane * 4;
  const float* Vb = V + (size_t)l * LVLN * DM;

  const int p0 = tix[(q * NLVL + l) * 4 + p];
  const int xw = p0 >> 6, yh = p0 & 63;
  float4 acc = {0.f, 0.f, 0.f, 0.f};

  if (p0 >= 65 && p0 <= 3904 && yh >= 1 && yh <= 62) {
    // fast path: 4x4 window, weights [1,2,2,1] x [1,2,2,1]
#pragma unroll
    for (int a = 0; a < 4; ++a) {
      const int y = yh - 2 + a;
      if (y < 0) continue;
      const float wa = (a == 1 || a == 2) ? 2.f : 1.f;
#pragma unroll
      for (int bb = 0; bb < 4; ++bb) {
        const int x = xw - 2 + bb;
        if (x < 0) continue;
        const float wb = (bb == 1 || bb == 2) ? 2.f : 1.f;
        const float4 v = *(const float4*)(Vb + (size_t)(y * 64 + x) * DM + c0);
        fma4v(acc, wa * wb, v);
      }
    }
  } else {
    // exact per-neighbor path with clip + border masks
    const int nei[9] = {-65, -64, -63, -1, 0, 1, 63, 64, 65};
#pragma unroll
    for (int n9 = 0; n9 < 9; ++n9) {
      int r = p0 + nei[n9];
      r = r < 0 ? 0 : (r > CLIPMX ? CLIPMX : r);
      const int x = r >> 6, y = r & 63;
      const int b0 = y * 64 + x;
      float4 s = *(const float4*)(Vb + (size_t)b0 * DM + c0);
      if (x > 0) {
        const float4 v = *(const float4*)(Vb + (size_t)(b0 - 1) * DM + c0);
        add4(s, v);
      }
      if (y > 0) {
        const float4 v = *(const float4*)(Vb + (size_t)(b0 - 64) * DM + c0);
        add4(s, v);
        if (x > 0) {
          const float4 u = *(const float4*)(Vb + (size_t)(b0 - 65) * DM + c0);
          add4(s, u);
        }
      }
      add4(acc, s);
    }
  }

  __shared__ __align__(16) float4 red[4][64];
  red[p][lane] = acc;
  __syncthreads();
  if (p == 0) {
    const float4 a0 = red[0][lane], a1 = red[1][lane];
    const float4 a2 = red[2][lane], a3 = red[3][lane];
    float4 s;
    s.x = (a0.x + a1.x) + (a2.x + a3.x);
    s.y = (a0.y + a1.y) + (a2.y + a3.y);
    s.z = (a0.z + a1.z) + (a2.z + a3.z);
    s.w = (a0.w + a1.w) + (a2.w + a3.w);
    *(float4*)(pre4 + ((size_t)l * LQ + q) * DM + c0) = s;
  }
}

// ---------- kernel C2: pre = (sum over 4 levels of pre4) * (0.25/144) ----------
__global__ __launch_bounds__(256) void sum4(
    const float* __restrict__ pre4, float* __restrict__ pre)
{
  const size_t i = (size_t)blockIdx.x * 256 + threadIdx.x;   // float4 index
  const size_t n = (size_t)LQ * DM / 4;
  const float4 a = ((const float4*)pre4)[i];
  const float4 b = ((const float4*)pre4)[i + n];
  const float4 c = ((const float4*)pre4)[i + 2 * n];
  const float4 d = ((const float4*)pre4)[i + 3 * n];
  const float k = 0.25f / 144.f;
  float4 s;
  s.x = ((a.x + b.x) + (c.x + d.x)) * k;
  s.y = ((a.y + b.y) + (c.y + d.y)) * k;
  s.z = ((a.z + b.z) + (c.z + d.z)) * k;
  s.w = ((a.w + b.w) + (c.w + d.w)) * k;
  ((float4*)pre)[i] = s;
}

// ---------- kernel D0: transpose out_w (256x256) ----------
__global__ void transp_w(const float* __restrict__ W, float* __restrict__ Wt)
{
  __shared__ float t[32][33];
  const int bx = blockIdx.x * 32, by = blockIdx.y * 32;
  t[threadIdx.y][threadIdx.x] = W[(size_t)(by + threadIdx.y) * DM + bx + threadIdx.x];
  __syncthreads();
  Wt[(size_t)(bx + threadIdx.y) * DM + by + threadIdx.x] = t[threadIdx.x][threadIdx.y];
}

// ---------- kernel D: out = pre @ W^T + b ----------
__global__ __launch_bounds__(256) void proj_out(
    const float* __restrict__ pre, const float* __restrict__ Wt,
    const float* __restrict__ bias, float* __restrict__ outp)
{
  const int q0 = blockIdx.x * QB;
  const int e = threadIdx.x;
  float acc[QB];
#pragma unroll
  for (int i = 0; i < QB; ++i) acc[i] = 0.f;
#pragma unroll 4
  for (int d = 0; d < DM; ++d) {
    const float w = Wt[(size_t)d * DM + e];
#pragma unroll
    for (int qq = 0; qq < QB; ++qq)
      acc[qq] = fmaf(pre[(size_t)(q0 + qq) * DM + d], w, acc[qq]);
  }
  const float be = bias[e];
#pragma unroll
  for (int qq = 0; qq < QB; ++qq)
    outp[(size_t)(q0 + qq) * DM + e] = acc[qq] + be;
}

extern "C" void kernel_launch(void* const* d_in, const int* in_sizes, int n_in,
                              void* d_out, int out_size, void* d_ws, size_t ws_size,
                              hipStream_t stream)
{
  const float* Q    = (const float*)d_in[0];   // [2048][256]
  const float* V    = (const float*)d_in[2];   // [16384][256]
  const float* W    = (const float*)d_in[5];   // [256][256]
  const float* bias = (const float*)d_in[6];   // [256]

  float* outp = (float*)d_out;                 // [2048][256]
  float* sloc = outp + (size_t)LQ * DM;        // [2048][4][36][2]

  char* ws = (char*)d_ws;
  const size_t CORR_B = (size_t)LQ * LVLN * 4; // 33.5 MB (proven available)

  float* corr = (float*)ws;
  int*   tix  = (int*)(ws + CORR_B);
  float* pre  = (float*)(ws + CORR_B + 131072);
  float* Wt   = (float*)(ws + CORR_B + 131072 + 2097152);
  // pre4 [4][2048][256] = 8 MB aliases corr (dead after last topk_loc)
  float* pre4 = corr;

  for (int l = 0; l < NLVL; ++l) {
    gemm_qk8<<<dim3(LQ / BM8, LVLN / BN8), 256, 0, stream>>>(
        Q, V + (size_t)l * LVLN * DM, corr);
    topk_loc<<<dim3(LQ / 4), 256, 0, stream>>>(corr, l, tix, sloc);
  }
  samp_acc4<<<dim3(LQ, NLVL), 256, 0, stream>>>(V, tix, pre4);
  sum4<<<dim3(LQ * DM / 1024), 256, 0, stream>>>(pre4, pre);
  transp_w<<<dim3(8, 8), dim3(32, 32), 0, stream>>>(W, Wt);
  proj_out<<<dim3(LQ / QB), 256, 0, stream>>>(pre, Wt, bias, outp);
}